// Round 5
// baseline (250.290 us; speedup 1.0000x reference)
//
#include <hip/hip_runtime.h>
#include <hip/hip_bf16.h>
#include <hip/hip_cooperative_groups.h>

namespace cg = cooperative_groups;

#define NN 4096
#define FF 128
#define NC 80     // 64 value cols + 8 expEr cols + 1 ones col + 7 pad
#define LSTR 84   // LDS partial-tile row stride in floats (84%32=20 -> 2-way max)

typedef __attribute__((ext_vector_type(4))) float float4v;
typedef __attribute__((ext_vector_type(4))) unsigned int uint4v;
typedef __attribute__((ext_vector_type(8))) short short8;

static __device__ inline unsigned short bfb(float x) {
    __hip_bfloat16 b = __float2bfloat16(x);
    return *(unsigned short*)&b;
}
static __device__ inline float bff(unsigned short u) {
    __hip_bfloat16 b = *(__hip_bfloat16*)&u;
    return __bfloat162float(b);
}

// ---------------------------------------------------------------------------
// Fused cooperative kernel: 256 blocks x 512 thr (1 block/CU, co-resident).
// Phase 0: W split (80x128 panel -> hi/lo bf16 B-fragment layout)
// Phase 1: prep  HW = H@W split-bf16, 16 rows/block, 4 waves; epilogue -> Bp
// Phase 2: gemm  block-local split-K over A row-tile, denom+elu+store
// Phase bodies are byte-equivalent to the round-4 standalone kernels; the
// fusion (a) removes 2 launch drains, (b) makes the whole workload a single
// dispatch large enough to surface in rocprof's top-5 with HBM/MFMA counters.
// ---------------------------------------------------------------------------
__global__ __launch_bounds__(512) void gat_fused(const float* __restrict__ A,
                                                 const float* __restrict__ H,
                                                 const float* __restrict__ W,
                                                 const float* __restrict__ al,
                                                 const float* __restrict__ ar,
                                                 float* __restrict__ expEl,
                                                 __hip_bfloat16* __restrict__ Bp,
                                                 __hip_bfloat16* __restrict__ Wphi,
                                                 __hip_bfloat16* __restrict__ Wplo,
                                                 float* __restrict__ out)
{
    __shared__ float Ls[8 * 16 * LSTR];   // 43 KB; prep uses first 21.5 KB
    cg::grid_group grid = cg::this_grid();

    // ================= Phase 0: W split (one element per thread) ===========
    {
        const int tid = blockIdx.x * 512 + threadIdx.x;   // 0..131071
        if (tid < 80 * FF) {
            const int c = tid % 80;
            const int f = tid / 80;                       // 0..127
            float val;
            if (c < 64) {
                val = W[(size_t)(c >> 3) * (FF * 8) + (size_t)f * 8 + (c & 7)];
            } else {
                const int hc = (c - 64) & 7;
                const float* ap = (c < 72) ? ar : al;
                const float* wp = W + (size_t)hc * (FF * 8) + (size_t)f * 8;
                float s = 0.f;
                #pragma unroll
                for (int u = 0; u < 8; ++u) s += wp[u] * ap[hc * 8 + u];
                val = s;
            }
            const unsigned short h = bfb(val);
            const unsigned short l = bfb(val - bff(h));
            const int g = (f >> 5) * 4 + ((f >> 3) & 3);
            const size_t idx = ((size_t)g * NC + c) * 8 + (f & 7);
            Wphi[idx] = *(const __hip_bfloat16*)&h;
            Wplo[idx] = *(const __hip_bfloat16*)&l;
        }
    }
    __threadfence();
    grid.sync();

    // ================= Phase 1: prep (threads < 256; 4 waves) ==============
    {
        const int t = threadIdx.x;
        if (t < 256) {
            const int wave = t >> 6;              // 0..3 = kt (K-slice of 32)
            const int lane = t & 63;
            const int j0   = blockIdx.x * 16;
            const int m16  = lane & 15, q = lane >> 4;
            const short* Whs = (const short*)Wphi;
            const short* Wls = (const short*)Wplo;
            const int kt = wave;

            const float* hp = H + (size_t)(j0 + m16) * FF + kt * 32 + q * 8;
            float4v x0 = *(const float4v*)hp;
            float4v x1 = *(const float4v*)(hp + 4);
            short8 ahi, alo;
            #pragma unroll
            for (int i = 0; i < 4; ++i) {
                const unsigned short h0 = bfb(x0[i]);
                ahi[i] = (short)h0;
                alo[i] = (short)bfb(x0[i] - bff(h0));
                const unsigned short h1 = bfb(x1[i]);
                ahi[4 + i] = (short)h1;
                alo[4 + i] = (short)bfb(x1[i] - bff(h1));
            }

            const short8* bh = (const short8*)(Whs + (size_t)(kt * 4 + q) * NC * 8);
            const short8* bl = (const short8*)(Wls + (size_t)(kt * 4 + q) * NC * 8);
            float4v acc[5] = {};
            #pragma unroll
            for (int nt = 0; nt < 5; ++nt) {
                short8 bhi = bh[nt * 16 + m16];
                short8 blo = bl[nt * 16 + m16];
                acc[nt] = __builtin_amdgcn_mfma_f32_16x16x32_bf16(ahi, bhi, acc[nt], 0, 0, 0);
                acc[nt] = __builtin_amdgcn_mfma_f32_16x16x32_bf16(alo, bhi, acc[nt], 0, 0, 0);
                acc[nt] = __builtin_amdgcn_mfma_f32_16x16x32_bf16(ahi, blo, acc[nt], 0, 0, 0);
            }

            float* Lw = Ls + wave * (16 * LSTR);
            #pragma unroll
            for (int nt = 0; nt < 5; ++nt) {
                #pragma unroll
                for (int r = 0; r < 4; ++r)   // C/D: col=lane&15, row=(lane>>4)*4+reg
                    Lw[(q * 4 + r) * LSTR + nt * 16 + m16] = acc[nt][r];
            }
        }
        __syncthreads();
        if (t < 256) {
            const int jl = t >> 4, g = t & 15;
            const int j0 = blockIdx.x * 16;
            const float* Lr = Ls + jl * LSTR;
            const int jg = j0 + jl;
            const size_t base = ((size_t)((jg >> 5) * 4 + ((jg >> 3) & 3)) * NC) * 8 + (jg & 7);

            #pragma unroll
            for (int i = 0; i < 4; ++i) {
                const int c = g + 16 * i;             // value col, h = c>>3
                const int h = (g >> 3) + 2 * i;
                const float er = expf(Lr[64 + h] + Lr[16 * LSTR + 64 + h] +
                                      Lr[32 * LSTR + 64 + h] + Lr[48 * LSTR + 64 + h]);
                const float v = Lr[c] + Lr[16 * LSTR + c] +
                                Lr[32 * LSTR + c] + Lr[48 * LSTR + c];
                Bp[base + (size_t)c * 8] = __float2bfloat16(er * v);
            }
            float v64;
            if (g < 8) {
                v64 = expf(Lr[64 + g] + Lr[16 * LSTR + 64 + g] +
                           Lr[32 * LSTR + 64 + g] + Lr[48 * LSTR + 64 + g]);
            } else {
                v64 = (g == 8) ? 1.0f : 0.0f;
            }
            Bp[base + (size_t)(64 + g) * 8] = __float2bfloat16(v64);
            if (g >= 8) {
                const int h = g - 8;
                expEl[h * NN + jg] = expf(Lr[72 + h] + Lr[16 * LSTR + 72 + h] +
                                          Lr[32 * LSTR + 72 + h] + Lr[48 * LSTR + 72 + h]);
            }
        }
    }
    __threadfence();
    grid.sync();
    __syncthreads();   // Ls handoff: prep epilogue reads done before gemm writes

    // ================= Phase 2: gemm (8 waves, block-local split-K) ========
    {
        const int rb   = blockIdx.x;          // 0..255, 16 rows each
        const int wave = threadIdx.x >> 6;    // 0..7 = K-chunk
        const int lane = threadIdx.x & 63;
        const int m16  = lane & 15;
        const int q    = lane >> 4;
        const int row0 = rb * 16;

        float4v acc[5] = {};

        const int k0 = wave * 512;
        const unsigned int* Au = (const unsigned int*)A;
        const short8* bb = (const short8*)Bp;
        const unsigned int* arow = Au + (size_t)(row0 + m16) * NN + q * 8 + k0;

        // B index (short8 units): (ktg*4+q)*NC + nt*16 + m16, ktg = wave*16+kt
        const size_t bw = (size_t)(wave * 16) * 4 * NC + (size_t)q * NC + (size_t)m16;

        // A-prefetch ring, depth 4
        uint4v a0[4], a1[4];
        #pragma unroll
        for (int i = 0; i < 4; ++i) {
            a0[i] = *(const uint4v*)(arow + i * 32);
            a1[i] = *(const uint4v*)(arow + i * 32 + 4);
        }
        // B double-buffer: preload kt=0
        short8 bbuf[2][5];
        #pragma unroll
        for (int nt = 0; nt < 5; ++nt)
            bbuf[0][nt] = bb[bw + (size_t)nt * 16];

        #pragma unroll
        for (int kt = 0; kt < 16; ++kt) {
            const int cur = kt & 3;           // static after full unroll
            const int pb  = kt & 1, nb = pb ^ 1;

            if (kt + 1 < 16) {
                #pragma unroll
                for (int nt = 0; nt < 5; ++nt)
                    bbuf[nb][nt] = bb[bw + (size_t)(kt + 1) * (4 * NC) + (size_t)nt * 16];
            }

            short8 afrag;
            afrag[0] = (short)(a0[cur][0] >> 16); afrag[1] = (short)(a0[cur][1] >> 16);
            afrag[2] = (short)(a0[cur][2] >> 16); afrag[3] = (short)(a0[cur][3] >> 16);
            afrag[4] = (short)(a1[cur][0] >> 16); afrag[5] = (short)(a1[cur][1] >> 16);
            afrag[6] = (short)(a1[cur][2] >> 16); afrag[7] = (short)(a1[cur][3] >> 16);

            if (kt + 4 < 16) {                // refill A ring
                a0[cur] = *(const uint4v*)(arow + (kt + 4) * 32);
                a1[cur] = *(const uint4v*)(arow + (kt + 4) * 32 + 4);
            }

            #pragma unroll
            for (int nt = 0; nt < 5; ++nt)
                acc[nt] = __builtin_amdgcn_mfma_f32_16x16x32_bf16(afrag, bbuf[pb][nt], acc[nt], 0, 0, 0);
        }

        // ---- partials -> LDS (stride LSTR=84) ----
        float* Lw = Ls + wave * (16 * LSTR);
        #pragma unroll
        for (int nt = 0; nt < 5; ++nt) {
            #pragma unroll
            for (int r = 0; r < 4; ++r)       // C/D: col=lane&15, row=(lane>>4)*4+reg
                Lw[(q * 4 + r) * LSTR + nt * 16 + m16] = acc[nt][r];
        }
        __syncthreads();

        // ---- reduce 8 wave-partials + denom + elu + store (1024 outputs) ----
        #pragma unroll
        for (int p = threadIdx.x; p < 1024; p += 512) {
            const int il = p >> 6;            // local row
            const int c  = p & 63;            // h*8+u
            const int h  = c >> 3;
            float T = 0.f, S = 0.f, dg = 0.f;
            #pragma unroll
            for (int w = 0; w < 8; ++w) {
                const float* rowp = Ls + w * (16 * LSTR) + il * LSTR;
                T  += rowp[c];
                S  += rowp[64 + h];
                dg += rowp[72];
            }
            const float el = expEl[h * NN + row0 + il];
            const float denom = ((float)NN - dg) + el * S;
            const float x = el * T / denom;
            out[(size_t)(row0 + il) * 64 + c] = x > 0.f ? x : expf(x) - 1.f;
        }
    }
}

extern "C" void kernel_launch(void* const* d_in, const int* in_sizes, int n_in,
                              void* d_out, int out_size, void* d_ws, size_t ws_size,
                              hipStream_t stream) {
    const float* A  = (const float*)d_in[0];
    const float* H  = (const float*)d_in[1];
    const float* W  = (const float*)d_in[2];
    const float* al = (const float*)d_in[3];
    const float* ar = (const float*)d_in[4];
    float* out = (float*)d_out;

    // workspace layout
    float* expEl = (float*)d_ws;                                    // 8*4096 f32 = 128 KB
    __hip_bfloat16* Bp   = (__hip_bfloat16*)((char*)d_ws + 131072); // 512*80*8 bf16 = 640 KB
    __hip_bfloat16* Wphi = (__hip_bfloat16*)((char*)d_ws + 131072 + 655360);          // 20 KB
    __hip_bfloat16* Wplo = (__hip_bfloat16*)((char*)d_ws + 131072 + 655360 + 20480);  // 20 KB

    void* args[] = {(void*)&A, (void*)&H, (void*)&W, (void*)&al, (void*)&ar,
                    (void*)&expEl, (void*)&Bp, (void*)&Wphi, (void*)&Wplo, (void*)&out};
    hipLaunchCooperativeKernel((void*)gat_fused, dim3(256), dim3(512), args, 0, stream);
}

// Round 6
// 117.594 us; speedup vs baseline: 2.1284x; 2.1284x over previous
//
#include <hip/hip_runtime.h>
#include <hip/hip_bf16.h>

#define NN 4096
#define FF 128
#define NC 80     // 64 value cols + 8 expEr cols + 1 ones col + 7 pad
#define LSTR 84   // LDS partial-tile row stride in floats (84%32=20 -> 2-way max)

typedef __attribute__((ext_vector_type(4))) float float4v;
typedef __attribute__((ext_vector_type(4))) unsigned int uint4v;
typedef __attribute__((ext_vector_type(8))) short short8;
typedef __attribute__((ext_vector_type(8))) unsigned short ushort8;

static __device__ inline unsigned short bfb(float x) {
    __hip_bfloat16 b = __float2bfloat16(x);
    return *(unsigned short*)&b;
}
static __device__ inline float bff(unsigned short u) {
    __hip_bfloat16 b = *(__hip_bfloat16*)&u;
    return __bfloat162float(b);
}

// ---------------------------------------------------------------------------
// Kernel 1 (MFMA prep): HW = H@W, split-bf16 (hi+lo, 3 cross-term MFMAs).
// 256 blocks x 256 thr (4 waves). W-split is staged per-block into LDS
// (round-0's proven pattern; W = 32 KB, an L2 broadcast -> redundancy is
// free and it removes the separate wsplit launch + Wp round-trip).
// Wave w owns K-slice kt=w (H loaded directly from global, split in regs);
// partials combined through LDS; epilogue writes Bp + expEl (no shuffles).
// ---------------------------------------------------------------------------
__global__ __launch_bounds__(256) void gat_prep(const float* __restrict__ H,
                                                const float* __restrict__ W,
                                                const float* __restrict__ al,
                                                const float* __restrict__ ar,
                                                float* __restrict__ expEl,
                                                __hip_bfloat16* __restrict__ Bp)
{
    __shared__ unsigned short Whi[16 * NC * 8], Wlo[16 * NC * 8];  // 40 KB
    __shared__ float Lp[4 * 16 * LSTR];                            // 21.5 KB
    const int t  = threadIdx.x;
    const int j0 = blockIdx.x * 16;

    // ---- stage W value-cols 0..63 in B-fragment layout (hi/lo) ----
    {
        const int hu = t & 63;          // column 0..63 (h*8+u)
        const int fb = (t >> 6) * 32;   // f-range per wave
        const float* wsrc = W + (size_t)(hu >> 3) * (FF * 8) + (hu & 7);
        #pragma unroll
        for (int g8 = 0; g8 < 4; ++g8) {
            const int f0 = fb + g8 * 8;
            ushort8 hv, lv;
            #pragma unroll
            for (int i = 0; i < 8; ++i) {
                float x = wsrc[(size_t)(f0 + i) * 8];
                unsigned short h = bfb(x);
                hv[i] = h; lv[i] = bfb(x - bff(h));
            }
            const int g = (f0 >> 5) * 4 + ((f0 >> 3) & 3);
            *(ushort8*)&Whi[((size_t)g * NC + hu) * 8] = hv;
            *(ushort8*)&Wlo[((size_t)g * NC + hu) * 8] = lv;
        }
    }
    // ---- build contracted cols: wr (64..71), wl (72..79) ----
    {
        const int h  = t >> 5;          // 0..7
        const int f0 = (t & 31) * 4;    // 4 f-values per thread
        float arv[8], alv[8];
        #pragma unroll
        for (int u = 0; u < 8; ++u) { arv[u] = ar[h * 8 + u]; alv[u] = al[h * 8 + u]; }
        #pragma unroll
        for (int i = 0; i < 4; ++i) {
            const int f = f0 + i;
            const float* wp = W + (size_t)h * (FF * 8) + (size_t)f * 8;
            float sr = 0.f, sl = 0.f;
            #pragma unroll
            for (int u = 0; u < 8; ++u) { float w = wp[u]; sr += w * arv[u]; sl += w * alv[u]; }
            const int g = (f >> 5) * 4 + ((f >> 3) & 3);
            unsigned short a = bfb(sr);
            Whi[((size_t)g * NC + 64 + h) * 8 + (f & 7)] = a;
            Wlo[((size_t)g * NC + 64 + h) * 8 + (f & 7)] = bfb(sr - bff(a));
            unsigned short b = bfb(sl);
            Whi[((size_t)g * NC + 72 + h) * 8 + (f & 7)] = b;
            Wlo[((size_t)g * NC + 72 + h) * 8 + (f & 7)] = bfb(sl - bff(b));
        }
    }
    __syncthreads();

    // ---- MFMA: wave w = K-slice kt, H direct from global ----
    {
        const int wave = t >> 6, lane = t & 63;
        const int m16 = lane & 15, q = lane >> 4;
        const int kt = wave;

        const float* hp = H + (size_t)(j0 + m16) * FF + kt * 32 + q * 8;
        float4v x0 = *(const float4v*)hp;
        float4v x1 = *(const float4v*)(hp + 4);
        short8 ahi, alo;
        #pragma unroll
        for (int i = 0; i < 4; ++i) {
            const unsigned short h0 = bfb(x0[i]);
            ahi[i] = (short)h0;
            alo[i] = (short)bfb(x0[i] - bff(h0));
            const unsigned short h1 = bfb(x1[i]);
            ahi[4 + i] = (short)h1;
            alo[4 + i] = (short)bfb(x1[i] - bff(h1));
        }

        float4v acc[5] = {};
        #pragma unroll
        for (int nt = 0; nt < 5; ++nt) {
            short8 bhi = *(const short8*)&Whi[((size_t)(kt * 4 + q) * NC + nt * 16 + m16) * 8];
            short8 blo = *(const short8*)&Wlo[((size_t)(kt * 4 + q) * NC + nt * 16 + m16) * 8];
            acc[nt] = __builtin_amdgcn_mfma_f32_16x16x32_bf16(ahi, bhi, acc[nt], 0, 0, 0);
            acc[nt] = __builtin_amdgcn_mfma_f32_16x16x32_bf16(alo, bhi, acc[nt], 0, 0, 0);
            acc[nt] = __builtin_amdgcn_mfma_f32_16x16x32_bf16(ahi, blo, acc[nt], 0, 0, 0);
        }

        // partial -> LDS (C/D layout: col=lane&15, row=(lane>>4)*4+reg)
        float* Lw = Lp + wave * (16 * LSTR);
        #pragma unroll
        for (int nt = 0; nt < 5; ++nt) {
            #pragma unroll
            for (int r = 0; r < 4; ++r)
                Lw[(q * 4 + r) * LSTR + nt * 16 + m16] = acc[nt][r];
        }
    }
    __syncthreads();

    // ---- epilogue: 256 thr, thread (jl = t>>4, g = t&15) ----
    const int jl = t >> 4, g = t & 15;
    const float* Lr = Lp + jl * LSTR;
    const int jg = j0 + jl;
    const size_t base = ((size_t)((jg >> 5) * 4 + ((jg >> 3) & 3)) * NC) * 8 + (jg & 7);

    #pragma unroll
    for (int i = 0; i < 4; ++i) {
        const int c = g + 16 * i;                 // value col, h = c>>3
        const int h = (g >> 3) + 2 * i;
        const float er = expf(Lr[64 + h] + Lr[16 * LSTR + 64 + h] +
                              Lr[32 * LSTR + 64 + h] + Lr[48 * LSTR + 64 + h]);
        const float v = Lr[c] + Lr[16 * LSTR + c] +
                        Lr[32 * LSTR + c] + Lr[48 * LSTR + c];
        Bp[base + (size_t)c * 8] = __float2bfloat16(er * v);
    }
    float v64;
    if (g < 8) {
        v64 = expf(Lr[64 + g] + Lr[16 * LSTR + 64 + g] +
                   Lr[32 * LSTR + 64 + g] + Lr[48 * LSTR + 64 + g]);
    } else {
        v64 = (g == 8) ? 1.0f : 0.0f;
    }
    Bp[base + (size_t)(64 + g) * 8] = __float2bfloat16(v64);
    if (g >= 8) {
        const int h = g - 8;
        expEl[h * NN + jg] = expf(Lr[72 + h] + Lr[16 * LSTR + 72 + h] +
                                  Lr[32 * LSTR + 72 + h] + Lr[48 * LSTR + 72 + h]);
    }
}

// ---------------------------------------------------------------------------
// Kernel 2 (fused, block-local split-K): 1024 thr (16 waves), 16 rows/block,
// wave w covers K-chunk [w*256,(w+1)*256). Round-5 counters showed the gemm
// is LATENCY-bound, not BW-bound (A is ~half L3-resident, FETCH 37 MB < 64;
// HBM 3% in fused probe), so the lever is occupancy: 16 waves/CU (4/SIMD)
// vs the previous 8 (2/SIMD). This is round-1's structure MINUS the
// non-temporal loads (NT forced the full 64 MB A through HBM -- the real
// round-1 regression, not the wave count). Plain loads keep L3 locality.
// 86 KB LDS, ~80 VGPR -> 1 block/CU, 16 waves resident.
// ---------------------------------------------------------------------------
__global__ __launch_bounds__(1024) void gat_gemm(const float* __restrict__ A,
                                                 const __hip_bfloat16* __restrict__ Bp,
                                                 const float* __restrict__ expEl,
                                                 float* __restrict__ out)
{
    __shared__ float Ls[16 * 16 * LSTR];  // 86 KB
    const int rb   = blockIdx.x;          // 0..255, 16 rows each
    const int wave = threadIdx.x >> 6;    // 0..15 = K-chunk
    const int lane = threadIdx.x & 63;
    const int m16  = lane & 15;
    const int q    = lane >> 4;
    const int row0 = rb * 16;

    float4v acc[5] = {};

    const int k0 = wave * 256;
    const unsigned int* Au = (const unsigned int*)A;
    const short* Bs = (const short*)Bp;
    const unsigned int* arow = Au + (size_t)(row0 + m16) * NN + q * 8 + k0;

    // A-prefetch ring, depth 2
    uint4v a0[2], a1[2];
    a0[0] = *(const uint4v*)(arow);      a1[0] = *(const uint4v*)(arow + 4);
    a0[1] = *(const uint4v*)(arow + 32); a1[1] = *(const uint4v*)(arow + 36);

    #pragma unroll
    for (int kt = 0; kt < 8; ++kt) {
        const int cur = kt & 1;           // static after full unroll
        short8 afrag;
        afrag[0] = (short)(a0[cur][0] >> 16); afrag[1] = (short)(a0[cur][1] >> 16);
        afrag[2] = (short)(a0[cur][2] >> 16); afrag[3] = (short)(a0[cur][3] >> 16);
        afrag[4] = (short)(a1[cur][0] >> 16); afrag[5] = (short)(a1[cur][1] >> 16);
        afrag[6] = (short)(a1[cur][2] >> 16); afrag[7] = (short)(a1[cur][3] >> 16);

        if (kt + 2 < 8) {                 // rolling prefetch
            a0[cur] = *(const uint4v*)(arow + (kt + 2) * 32);
            a1[cur] = *(const uint4v*)(arow + (kt + 2) * 32 + 4);
        }

        const int ktg = wave * 8 + kt;    // global 32-wide k-tile index
        const short8* bbase = (const short8*)(Bs + ((size_t)(ktg * 4 + q) * NC) * 8);
        #pragma unroll
        for (int nt = 0; nt < 5; ++nt) {
            short8 bfrag = bbase[nt * 16 + m16];
            acc[nt] = __builtin_amdgcn_mfma_f32_16x16x32_bf16(afrag, bfrag, acc[nt], 0, 0, 0);
        }
    }

    // ---- partials -> LDS (stride LSTR=84: q-groups land 16 banks apart) ----
    float* Lw = Ls + wave * (16 * LSTR);
    #pragma unroll
    for (int nt = 0; nt < 5; ++nt) {
        #pragma unroll
        for (int r = 0; r < 4; ++r)       // C/D: col=lane&15, row=(lane>>4)*4+reg
            Lw[(q * 4 + r) * LSTR + nt * 16 + m16] = acc[nt][r];
    }
    __syncthreads();

    // ---- reduce 16 wave-partials + denom + elu + store (1024 outputs) ----
    {
        const int p  = threadIdx.x;
        const int il = p >> 6;            // local row
        const int c  = p & 63;            // h*8+u
        const int h  = c >> 3;
        float T = 0.f, S = 0.f, dg = 0.f;
        #pragma unroll
        for (int w = 0; w < 16; ++w) {
            const float* rowp = Ls + w * (16 * LSTR) + il * LSTR;
            T  += rowp[c];
            S  += rowp[64 + h];
            dg += rowp[72];
        }
        const float el = expEl[h * NN + row0 + il];
        const float denom = ((float)NN - dg) + el * S;
        const float x = el * T / denom;
        out[(size_t)(row0 + il) * 64 + c] = x > 0.f ? x : expf(x) - 1.f;
    }
}

extern "C" void kernel_launch(void* const* d_in, const int* in_sizes, int n_in,
                              void* d_out, int out_size, void* d_ws, size_t ws_size,
                              hipStream_t stream) {
    const float* A  = (const float*)d_in[0];
    const float* H  = (const float*)d_in[1];
    const float* W  = (const float*)d_in[2];
    const float* al = (const float*)d_in[3];
    const float* ar = (const float*)d_in[4];
    float* out = (float*)d_out;

    // workspace layout
    float* expEl = (float*)d_ws;                                   // 8*4096 f32 = 128 KB
    __hip_bfloat16* Bp = (__hip_bfloat16*)((char*)d_ws + 131072);  // 512*80*8 bf16 = 640 KB

    gat_prep<<<NN / 16, 256, 0, stream>>>(H, W, al, ar, expEl, Bp);
    gat_gemm<<<NN / 16, 1024, 0, stream>>>(A, Bp, expEl, out);
}